// Round 5
// baseline (134.700 us; speedup 1.0000x reference)
//
#include <hip/hip_runtime.h>
#include <hip/hip_fp16.h>

// Bilinear grid-sample on v[B,C,H,W] f32, per-pixel random query coords.
// Round 5: kill the vt HBM refetch (L3 won't retain it) by making gathers
// L2-resident:
//  - vt split into two half-channel tensors [B][HW][8] f16 (16 B/px each),
//    processed in two temporally-separate passes;
//  - batch-per-XCD swizzle (b = blockIdx.x & 7): each XCD gathers only from
//    its own batch's half-image = 4 MiB = exactly its L2. No cross-XCD
//    redundant caching, no L3 dependence.

#define BATCH 8
#define CHAN  16
#define HEIGHT 512
#define WIDTH  512
#define HW (HEIGHT * WIDTH)
#define BLOCKS_PER_BATCH (HW / 256)   // 1024

// --- pass 1: BCHW f32 -> two BHWC-half f16 tensors --------------------------
// Swizzled the same way as the gather so each XCD's L2 ends warm with (some
// of) its own batch. v reads non-temporal (single touch).
__global__ __launch_bounds__(256) void transpose_split_f16(
    const float* __restrict__ v, __half* __restrict__ vt0, __half* __restrict__ vt1)
{
    const int blk = blockIdx.x;
    const int b = blk & 7;
    const int j = blk >> 3;
    const int p = j * 256 + threadIdx.x;   // pixel within batch
    const int tid = b * HW + p;

    const float* src = v + (size_t)b * CHAN * HW + p;

    __half2 d[8];
#pragma unroll
    for (int j2 = 0; j2 < 8; ++j2) {
        const float lo = __builtin_nontemporal_load(&src[(size_t)(2 * j2 + 0) * HW]);
        const float hi = __builtin_nontemporal_load(&src[(size_t)(2 * j2 + 1) * HW]);
        d[j2] = __floats2half2_rn(lo, hi);
    }

    *(uint4*)(vt0 + (size_t)tid * 8) = *(const uint4*)&d[0];  // channels 0..7
    *(uint4*)(vt1 + (size_t)tid * 8) = *(const uint4*)&d[4];  // channels 8..15
}

// --- pass 2/3: gather 8 channels from one half-tensor, write BCHW ----------
__global__ __launch_bounds__(256) void interp2_half8(
    const __half* __restrict__ vth,   // [B][HW][8] f16
    const float* __restrict__ xq,
    const float* __restrict__ yq,
    float* __restrict__ out,          // [B][CHAN][HW]
    int c0)                           // first output channel (0 or 8)
{
    const int blk = blockIdx.x;
    const int b = blk & 7;            // batch == XCD (round-robin dispatch)
    const int j = blk >> 3;
    const int p = j * 256 + threadIdx.x;   // pixel within batch
    const int qidx = b * HW + p;

    const float xqv = __builtin_nontemporal_load(&xq[qidx]);
    const float yqv = __builtin_nontemporal_load(&yq[qidx]);

    const bool invalid = (xqv < 0.0f) | (xqv >= (float)WIDTH) |
                         (yqv < 0.0f) | (yqv >= (float)HEIGHT);

    int x0 = (int)floorf(xqv);
    int y0 = (int)floorf(yqv);
    x0 = min(max(x0, 0), WIDTH - 1);
    y0 = min(max(y0, 0), HEIGHT - 1);
    const int x1 = min(x0 + 1, WIDTH - 1);
    const int y1 = min(y0 + 1, HEIGHT - 1);

    const float dx = xqv - (float)x0;
    const float dy = yqv - (float)y0;

    float w00 = (1.0f - dy) * (1.0f - dx);
    float w01 = (1.0f - dy) * dx;
    float w10 = dy * (1.0f - dx);
    float w11 = dy * dx;
    if (invalid) { w00 = 0.0f; w01 = 0.0f; w10 = 0.0f; w11 = 0.0f; }

    const size_t bbase = (size_t)b * HW;

    float acc[8];
#pragma unroll
    for (int c = 0; c < 8; ++c) acc[c] = 0.0f;

    auto corner = [&](int y, int x, float w) {
        const uint4 a = *(const uint4*)(vth + (bbase + (size_t)y * WIDTH + x) * 8);
        const __half2* h = (const __half2*)&a;
#pragma unroll
        for (int k = 0; k < 4; ++k) {
            const float2 f = __half22float2(h[k]);
            acc[2 * k + 0] += w * f.x;
            acc[2 * k + 1] += w * f.y;
        }
    };

    corner(y0, x0, w00);
    corner(y0, x1, w01);
    corner(y1, x0, w10);
    corner(y1, x1, w11);

    // BCHW output, 8 channels; nt stores keep the write stream out of L2.
    const size_t obase = (size_t)b * CHAN * HW + (size_t)c0 * HW + p;
#pragma unroll
    for (int c = 0; c < 8; ++c)
        __builtin_nontemporal_store(acc[c], &out[obase + (size_t)c * HW]);
}

// --- fallback (BCHW direct) if ws too small --------------------------------
__global__ __launch_bounds__(256) void interp2_bchw(
    const float* __restrict__ v,
    const float* __restrict__ xq,
    const float* __restrict__ yq,
    float* __restrict__ out)
{
    const int tid = blockIdx.x * blockDim.x + threadIdx.x;
    if (tid >= BATCH * HW) return;

    const int b   = tid / HW;
    const int pix = tid - b * HW;

    const float xqv = xq[tid];
    const float yqv = yq[tid];
    const bool invalid = (xqv < 0.0f) | (xqv >= (float)WIDTH) |
                         (yqv < 0.0f) | (yqv >= (float)HEIGHT);

    int x0 = (int)floorf(xqv);
    int y0 = (int)floorf(yqv);
    x0 = min(max(x0, 0), WIDTH - 1);
    y0 = min(max(y0, 0), HEIGHT - 1);
    const int x1 = min(x0 + 1, WIDTH - 1);
    const int y1 = min(y0 + 1, HEIGHT - 1);

    const float dx = xqv - (float)x0;
    const float dy = yqv - (float)y0;
    float w00 = (1.0f - dy) * (1.0f - dx);
    float w01 = (1.0f - dy) * dx;
    float w10 = dy * (1.0f - dx);
    float w11 = dy * dx;
    if (invalid) { w00 = 0.0f; w01 = 0.0f; w10 = 0.0f; w11 = 0.0f; }

    const int off00 = y0 * WIDTH + x0;
    const int off01 = y0 * WIDTH + x1;
    const int off10 = y1 * WIDTH + x0;
    const int off11 = y1 * WIDTH + x1;

    const int vbase = b * CHAN * HW;
    const int obase = vbase + pix;
#pragma unroll
    for (int c = 0; c < CHAN; ++c) {
        const int cb = vbase + c * HW;
        out[obase + c * HW] = v[cb + off00] * w00 + v[cb + off01] * w01 +
                              v[cb + off10] * w10 + v[cb + off11] * w11;
    }
}

extern "C" void kernel_launch(void* const* d_in, const int* in_sizes, int n_in,
                              void* d_out, int out_size, void* d_ws, size_t ws_size,
                              hipStream_t stream) {
    const float* v  = (const float*)d_in[0];
    const float* xq = (const float*)d_in[1];
    const float* yq = (const float*)d_in[2];
    float* out = (float*)d_out;

    const int grid = BATCH * BLOCKS_PER_BATCH;   // 8192 blocks, 256 thr
    const size_t half_bytes = (size_t)BATCH * HW * 8 * sizeof(__half);  // 32 MiB

    if (ws_size >= 2 * half_bytes) {
        __half* vt0 = (__half*)d_ws;
        __half* vt1 = (__half*)((char*)d_ws + half_bytes);
        transpose_split_f16<<<grid, 256, 0, stream>>>(v, vt0, vt1);
        interp2_half8<<<grid, 256, 0, stream>>>(vt0, xq, yq, out, 0);
        interp2_half8<<<grid, 256, 0, stream>>>(vt1, xq, yq, out, 8);
    } else {
        const int npix = BATCH * HW;
        interp2_bchw<<<(npix + 255) / 256, 256, 0, stream>>>(v, xq, yq, out);
    }
}